// Round 4
// baseline (1001.939 us; speedup 1.0000x reference)
//
#include <hip/hip_runtime.h>
#include <math.h>

#define M_ROWS 131072
#define D_DIM 256
#define NCODES 1024
#define QELEMS (M_ROWS * D_DIM)  // 33554432

typedef __attribute__((ext_vector_type(8))) short short8v;
typedef __attribute__((ext_vector_type(4))) float f32x4;
typedef unsigned short ushort_t;

// workspace layout (bytes)
#define WS_EMBEDT 0u          // 1024*256*4 = 1048576
#define WS_B1     1048576u    // 524288 (bf16 hi of codebook; frag-order fast / plain slow)
#define WS_B2     1572864u    // 524288 (bf16 lo)
#define WS_ENORM  2097152u    // 4096
#define WS_PART   2101248u    // 8*131072*16 = 16777216
#define WS_IDX2   18878464u   // 1048576
#define WS_COUNTS 19927040u   // 4096
#define WS_LOSSP  19931136u   // 32768  -> slow-path total 19963904
#define WS_XHI    19963904u   // 67108864 (frag-order bf16-hi of inputs)
#define WS_XLO    87072768u   // 67108864
#define WS_FAST_TOTAL 154181632u

// truncation bf16 split helpers (v_perm packs two hi-halves in 1 instr)
__device__ inline unsigned pack2(float x, float y) {
  return __builtin_amdgcn_perm(__float_as_uint(y), __float_as_uint(x), 0x07060302u);
}
__device__ inline float rem1(float x) {
  return x - __uint_as_float(__float_as_uint(x) & 0xFFFF0000u);
}
__device__ inline void split8(float4 a, float4 b, uint4* hi, uint4* lo) {
  *hi = make_uint4(pack2(a.x, a.y), pack2(a.z, a.w), pack2(b.x, b.y), pack2(b.z, b.w));
  *lo = make_uint4(pack2(rem1(a.x), rem1(a.y)), pack2(rem1(a.z), rem1(a.w)),
                   pack2(rem1(b.x), rem1(b.y)), pack2(rem1(b.z), rem1(b.w)));
}

// merge candidate top-2 into running top-2; tie -> lower index
__device__ inline void merge2(float& b0, int& i0, float& b1, int& i1,
                              float o0, int oi0, float o1, int oi1) {
  if (o0 < b0 || (o0 == b0 && oi0 < i0)) {
    if (b0 < o1 || (b0 == o1 && i0 < oi1)) { b1 = b0; i1 = i0; }
    else { b1 = o1; i1 = oi1; }
    b0 = o0; i0 = oi0;
  } else {
    if (o0 < b1 || (o0 == b1 && oi0 < i1)) { b1 = o0; i1 = oi0; }
  }
}

// ---------------------------------------------------------------------------
// Prep: embedT fp32 (gather/rescore), bf16 hi/lo of codebook (frag-order in
// fast mode, plain [code][k] in slow mode), per-code norms.
// Frag-order: record (cg,kc,ti) holds lane L's 8 ushorts at L*8; lane=quad*16+lm,
// col = cg*64 + ti*16 + lm, k = kc*32 + quad*8 + j.
__global__ __launch_bounds__(256) void k_prep(const float* __restrict__ embed,
                                              float* __restrict__ embedT,
                                              ushort_t* __restrict__ b1,
                                              ushort_t* __restrict__ b2,
                                              float* __restrict__ enorm, int fast) {
  int c = blockIdx.x, t = threadIdx.x;  // c = code, t = k
  float v = embed[t * NCODES + c];
  embedT[c * D_DIM + t] = v;
  unsigned bits = __float_as_uint(v);
  ushort_t hi = (ushort_t)(bits >> 16);
  ushort_t lo = (ushort_t)(__float_as_uint(rem1(v)) >> 16);
  if (fast) {
    int cg = c >> 6, ti = (c >> 4) & 3, lm = c & 15;
    int kc = t >> 5, quad = (t >> 3) & 3, j = t & 7;
    int lane = quad * 16 + lm;
    size_t off = ((size_t)((cg * 8 + kc) * 4 + ti) * 64 + lane) * 8 + j;
    b1[off] = hi; b2[off] = lo;
  } else {
    b1[c * D_DIM + t] = hi;
    b2[c * D_DIM + t] = lo;
  }
  float s = v * v;
  for (int off = 32; off > 0; off >>= 1) s += __shfl_down(s, off, 64);
  __shared__ float red[4];
  if ((t & 63) == 0) red[t >> 6] = s;
  __syncthreads();
  if (t == 0) enorm[c] = red[0] + red[1] + red[2] + red[3];
}

// ---------------------------------------------------------------------------
// Pre-split inputs into bf16 hi/lo in MFMA frag-order.
// Record (g,kc,ti): row = g*64 + ti*16 + lm, k = kc*32 + quad*8 + j.
// Block = one g-group (64 rows); thread t: ti=t>>6, lane=t&63.
__global__ __launch_bounds__(256) void k_asplit(const float* __restrict__ x,
                                                ushort_t* __restrict__ xhi,
                                                ushort_t* __restrict__ xlo) {
  int g = blockIdx.x, t = threadIdx.x;
  int ti = t >> 6, lane = t & 63;
  int quad = lane >> 4, lm = lane & 15;
  int row = g * 64 + ti * 16 + lm;
  const float* src = x + (size_t)row * D_DIM + quad * 8;
  size_t dst = (size_t)g * 16384 + ti * 512 + (size_t)lane * 8;
#pragma unroll
  for (int kc = 0; kc < 8; ++kc) {
    float4 v0 = *(const float4*)(src + kc * 32);
    float4 v1 = *(const float4*)(src + kc * 32 + 4);
    uint4 h, l;
    split8(v0, v1, &h, &l);
    *(uint4*)&xhi[dst + (size_t)kc * 2048] = h;
    *(uint4*)&xlo[dst + (size_t)kc * 2048] = l;
  }
}

// ---------------------------------------------------------------------------
// Shared epilogue for both k_dist variants.
__device__ inline void dist_epilogue(f32x4 (&acc)[4][4], const float* __restrict__ enorm,
                                     float4* __restrict__ partials, float4 (*sRed)[128],
                                     int t, int wr, int wc, int lm, int quad,
                                     int rowBase, int colBase, int ct) {
  float enC[4]; int cidx[4];
#pragma unroll
  for (int j = 0; j < 4; ++j) {
    cidx[j] = colBase + (wc << 6) + (j << 4) + lm;
    enC[j] = enorm[cidx[j]];
  }
#pragma unroll
  for (int ti = 0; ti < 4; ++ti) {
#pragma unroll
    for (int reg = 0; reg < 4; ++reg) {
      float b0 = 3.0e38f, b1 = 3.0e38f;
      int i0 = 0x7fffffff, i1 = 0x7fffffff;
#pragma unroll
      for (int j = 0; j < 4; ++j) {
        float v = fmaf(-2.f, acc[ti][j][reg], enC[j]);
        int c = cidx[j];
        if (v < b0 || (v == b0 && c < i0)) { b1 = b0; i1 = i0; b0 = v; i0 = c; }
        else if (v < b1 || (v == b1 && c < i1)) { b1 = v; i1 = c; }
      }
      for (int m = 1; m < 16; m <<= 1) {
        float o0 = __shfl_xor(b0, m, 64); int oi0 = __shfl_xor(i0, m, 64);
        float o1 = __shfl_xor(b1, m, 64); int oi1 = __shfl_xor(i1, m, 64);
        merge2(b0, i0, b1, i1, o0, oi0, o1, oi1);
      }
      if (lm == 0) {
        int rloc = (wr << 6) + (ti << 4) + (quad << 2) + reg;
        sRed[wc][rloc] = make_float4(b0, (float)i0, b1, (float)i1);
      }
    }
  }
  __syncthreads();
  if (t < 128) {
    float4 p = sRed[0][t];
    float b0 = p.x; int i0 = (int)p.y; float b1 = p.z; int i1 = (int)p.w;
    float4 q = sRed[1][t];
    merge2(b0, i0, b1, i1, q.x, (int)q.y, q.z, (int)q.w);
    partials[(size_t)ct * M_ROWS + rowBase + t] = make_float4(b0, (float)i0, b1, (float)i1);
  }
}

// ---------------------------------------------------------------------------
// FAST: LDS-free K-loop. All fragments loaded directly from frag-order global
// arrays (coalesced dwordx4, lane L at offset L*16). No barriers in the loop;
// compiler pipelines loads across kc freely.
__global__ __launch_bounds__(256, 3) void k_dist_fast(const ushort_t* __restrict__ xhi,
                                                      const ushort_t* __restrict__ xlo,
                                                      const ushort_t* __restrict__ bhi,
                                                      const ushort_t* __restrict__ blo,
                                                      const float* __restrict__ enorm,
                                                      float4* __restrict__ partials) {
  __shared__ float4 sRed[2][128];

  int bx = blockIdx.x;
  int xcd = bx & 7, slot = bx >> 3;
  int rt = (xcd << 7) | (slot >> 3);
  int ct = slot & 7;
  int rowBase = rt << 7, colBase = ct << 7;
  int t = threadIdx.x;
  int w = t >> 6, lane = t & 63;
  int wr = w >> 1, wc = w & 1;
  int lm = lane & 15, quad = lane >> 4;

  int g = rt * 2 + wr;    // A frag group (64 rows)
  int cg = ct * 2 + wc;   // B frag group (64 cols)

  const ushort_t* pAh = xhi + (size_t)g * 16384 + (size_t)lane * 8;
  const ushort_t* pAl = xlo + (size_t)g * 16384 + (size_t)lane * 8;
  const ushort_t* pBh = bhi + (size_t)cg * 16384 + (size_t)lane * 8;
  const ushort_t* pBl = blo + (size_t)cg * 16384 + (size_t)lane * 8;

  f32x4 acc[4][4];
#pragma unroll
  for (int i = 0; i < 4; ++i)
#pragma unroll
    for (int j = 0; j < 4; ++j) acc[i][j] = (f32x4){0.f, 0.f, 0.f, 0.f};

#pragma unroll
  for (int kc = 0; kc < 8; ++kc) {
    int base = kc * 2048;
    short8v ahi_f[4], alo_f[4], bhi_f[4], blo_f[4];
#pragma unroll
    for (int i = 0; i < 4; ++i) {
      ahi_f[i] = *(const short8v*)(pAh + base + i * 512);
      bhi_f[i] = *(const short8v*)(pBh + base + i * 512);
      blo_f[i] = *(const short8v*)(pBl + base + i * 512);
      alo_f[i] = *(const short8v*)(pAl + base + i * 512);
    }
#pragma unroll
    for (int i = 0; i < 4; ++i)
#pragma unroll
      for (int j = 0; j < 4; ++j)
        acc[i][j] = __builtin_amdgcn_mfma_f32_16x16x32_bf16(ahi_f[i], bhi_f[j], acc[i][j], 0, 0, 0);
#pragma unroll
    for (int i = 0; i < 4; ++i)
#pragma unroll
      for (int j = 0; j < 4; ++j)
        acc[i][j] = __builtin_amdgcn_mfma_f32_16x16x32_bf16(ahi_f[i], blo_f[j], acc[i][j], 0, 0, 0);
#pragma unroll
    for (int i = 0; i < 4; ++i)
#pragma unroll
      for (int j = 0; j < 4; ++j)
        acc[i][j] = __builtin_amdgcn_mfma_f32_16x16x32_bf16(alo_f[i], bhi_f[j], acc[i][j], 0, 0, 0);
  }

  dist_epilogue(acc, enorm, partials, sRed, t, wr, wc, lm, quad, rowBase, colBase, ct);
}

// ---------------------------------------------------------------------------
// SLOW fallback (small ws): R2/R3 structure with corrected XOR swizzle
// (u ^ ((r>>1)&3) -> 2-way bank aliasing = free).
__global__ __launch_bounds__(256, 3) void k_dist_slow(const float* __restrict__ A,
                                                      const ushort_t* __restrict__ ehiT,
                                                      const ushort_t* __restrict__ eloT,
                                                      const float* __restrict__ enorm,
                                                      float4* __restrict__ partials) {
  __shared__ ushort_t sAhi[4096], sAlo[4096], sBhi[4096], sBlo[4096];
  __shared__ float4 sRed[2][128];

  int bx = blockIdx.x;
  int ct = bx & 7, rt = bx >> 3;
  int rowBase = rt << 7, colBase = ct << 7;
  int t = threadIdx.x;
  int w = t >> 6, lane = t & 63;
  int wr = w >> 1, wc = w & 1;
  int lm = lane & 15, quad = lane >> 4;
  int sr = t >> 1;
  int skh = (t & 1) << 4;

  f32x4 acc[4][4];
#pragma unroll
  for (int i = 0; i < 4; ++i)
#pragma unroll
    for (int j = 0; j < 4; ++j) acc[i][j] = (f32x4){0.f, 0.f, 0.f, 0.f};

  int aoff[4], boff[4];
#pragma unroll
  for (int ti = 0; ti < 4; ++ti) {
    int r = (wr << 6) + (ti << 4) + lm;
    aoff[ti] = r * 32 + ((quad ^ ((r >> 1) & 3)) << 3);
    int n = (wc << 6) + (ti << 4) + lm;
    boff[ti] = n * 32 + ((quad ^ ((n >> 1) & 3)) << 3);
  }

  const float* Arow = A + (size_t)(rowBase + sr) * D_DIM + skh;
  const ushort_t* Bhirow = ehiT + (size_t)(colBase + sr) * D_DIM + skh;
  const ushort_t* Blorow = eloT + (size_t)(colBase + sr) * D_DIM + skh;
  int ssw = (sr >> 1) & 3;

  for (int kc = 0; kc < D_DIM; kc += 32) {
#pragma unroll
    for (int u = 0; u < 4; ++u) {
      float4 v = *(const float4*)(Arow + kc + (u << 2));
      int koff = skh + (u << 2);
      int dst = sr * 32 + (((koff >> 3) ^ ssw) << 3) + (koff & 7);
      *(uint2*)&sAhi[dst] = make_uint2(pack2(v.x, v.y), pack2(v.z, v.w));
      *(uint2*)&sAlo[dst] = make_uint2(pack2(rem1(v.x), rem1(v.y)), pack2(rem1(v.z), rem1(v.w)));
    }
#pragma unroll
    for (int h = 0; h < 2; ++h) {
      int koff = skh + (h << 3);
      int dst = sr * 32 + (((koff >> 3) ^ ssw) << 3);
      *(uint4*)&sBhi[dst] = *(const uint4*)(Bhirow + kc + (h << 3));
      *(uint4*)&sBlo[dst] = *(const uint4*)(Blorow + kc + (h << 3));
    }
    __syncthreads();

    short8v ahi[4], bhi_f[4], blo_f[4], alo[4];
#pragma unroll
    for (int i = 0; i < 4; ++i) {
      ahi[i] = *(const short8v*)&sAhi[aoff[i]];
      bhi_f[i] = *(const short8v*)&sBhi[boff[i]];
      blo_f[i] = *(const short8v*)&sBlo[boff[i]];
      alo[i] = *(const short8v*)&sAlo[aoff[i]];
    }
#pragma unroll
    for (int i = 0; i < 4; ++i)
#pragma unroll
      for (int j = 0; j < 4; ++j)
        acc[i][j] = __builtin_amdgcn_mfma_f32_16x16x32_bf16(ahi[i], bhi_f[j], acc[i][j], 0, 0, 0);
#pragma unroll
    for (int i = 0; i < 4; ++i)
#pragma unroll
      for (int j = 0; j < 4; ++j)
        acc[i][j] = __builtin_amdgcn_mfma_f32_16x16x32_bf16(ahi[i], blo_f[j], acc[i][j], 0, 0, 0);
#pragma unroll
    for (int i = 0; i < 4; ++i)
#pragma unroll
      for (int j = 0; j < 4; ++j)
        acc[i][j] = __builtin_amdgcn_mfma_f32_16x16x32_bf16(alo[i], bhi_f[j], acc[i][j], 0, 0, 0);
    __syncthreads();
  }

  dist_epilogue(acc, enorm, partials, sRed, t, wr, wc, lm, quad, rowBase, colBase, ct);
}

// ---------------------------------------------------------------------------
__global__ __launch_bounds__(256) void k_argmin(const float4* __restrict__ partials,
                                                int2* __restrict__ idx2) {
  int row = blockIdx.x * 256 + threadIdx.x;
  float b0 = 3.0e38f, b1 = 3.0e38f;
  int i0 = 0x7fffffff, i1 = 0x7fffffff;
#pragma unroll
  for (int tp = 0; tp < 8; ++tp) {
    float4 p = partials[(size_t)tp * M_ROWS + row];
    merge2(b0, i0, b1, i1, p.x, (int)p.y, p.z, (int)p.w);
  }
  idx2[row] = make_int2(i0, i1);
}

// ---------------------------------------------------------------------------
__global__ __launch_bounds__(256) void k_quant(const float* __restrict__ x,
                                               const float* __restrict__ embedT,
                                               const int2* __restrict__ idx2,
                                               float* __restrict__ outq,
                                               float* __restrict__ out_ind,
                                               int* __restrict__ counts,
                                               float* __restrict__ lossPart) {
  int b = blockIdx.x, t = threadIdx.x;
  int rl = t >> 6, lane = t & 63;
  float lsum = 0.f;
  __shared__ float red[4];
#pragma unroll
  for (int ri = 0; ri < 4; ++ri) {
    int row = b * 16 + ri * 4 + rl;
    int2 cc = idx2[row];
    float4 xv = *(const float4*)(x + (size_t)row * D_DIM + (lane << 2));
    float4 q0 = *(const float4*)(embedT + (size_t)cc.x * D_DIM + (lane << 2));
    float4 q1 = *(const float4*)(embedT + (size_t)cc.y * D_DIM + (lane << 2));
    float a0 = q0.x - xv.x, a1 = q0.y - xv.y, a2 = q0.z - xv.z, a3 = q0.w - xv.w;
    float c0 = q1.x - xv.x, c1 = q1.y - xv.y, c2 = q1.z - xv.z, c3 = q1.w - xv.w;
    float d0 = fmaf(a0, a0, fmaf(a1, a1, fmaf(a2, a2, a3 * a3)));
    float d1 = fmaf(c0, c0, fmaf(c1, c1, fmaf(c2, c2, c3 * c3)));
    for (int m = 1; m < 64; m <<= 1) {
      d0 += __shfl_xor(d0, m, 64);
      d1 += __shfl_xor(d1, m, 64);
    }
    bool sel = (d1 < d0) || (d1 == d0 && cc.y < cc.x);
    int widx = sel ? cc.y : cc.x;
    float4 qv;
    qv.x = sel ? q1.x : q0.x; qv.y = sel ? q1.y : q0.y;
    qv.z = sel ? q1.z : q0.z; qv.w = sel ? q1.w : q0.w;
    float4 o = make_float4(xv.x + (qv.x - xv.x), xv.y + (qv.y - xv.y),
                           xv.z + (qv.z - xv.z), xv.w + (qv.w - xv.w));
    *(float4*)(outq + (size_t)row * D_DIM + (lane << 2)) = o;
    lsum += sel ? d1 : d0;
    if (lane == 0) {
      out_ind[row] = (float)widx;
      atomicAdd(&counts[widx], 1);
    }
  }
  if (lane == 0) red[rl] = lsum;
  __syncthreads();
  if (t == 0) lossPart[b] = red[0] + red[1] + red[2] + red[3];
}

// ---------------------------------------------------------------------------
__global__ __launch_bounds__(1024) void k_final(const int* __restrict__ counts,
                                                const float* __restrict__ lossPart,
                                                float* __restrict__ out_scalars) {
  int t = threadIdx.x;
  double ls = 0.0;
#pragma unroll
  for (int u = 0; u < 8; ++u) ls += (double)lossPart[t * 8 + u];
  float p = (float)counts[t] * (1.0f / (float)M_ROWS);
  float ent = p * logf(p + 1e-10f);
  double lred = ls;
  float ered = ent;
  for (int off = 32; off > 0; off >>= 1) {
    lred += __shfl_down(lred, off, 64);
    ered += __shfl_down(ered, off, 64);
  }
  __shared__ double lsh[16];
  __shared__ float esh[16];
  int w = t >> 6;
  if ((t & 63) == 0) { lsh[w] = lred; esh[w] = ered; }
  __syncthreads();
  if (t == 0) {
    double L = 0.0;
    float E = 0.f;
    for (int i = 0; i < 16; ++i) { L += lsh[i]; E += esh[i]; }
    out_scalars[0] = (float)(L / (double)QELEMS);
    out_scalars[1] = expf(-E);
  }
}

// ---------------------------------------------------------------------------
extern "C" void kernel_launch(void* const* d_in, const int* in_sizes, int n_in,
                              void* d_out, int out_size, void* d_ws, size_t ws_size,
                              hipStream_t stream) {
  const float* inputs = (const float*)d_in[0];  // [131072,256]
  const float* embed = (const float*)d_in[1];   // [256,1024]
  float* out = (float*)d_out;
  char* ws = (char*)d_ws;
  float* embedT = (float*)(ws + WS_EMBEDT);
  ushort_t* b1 = (ushort_t*)(ws + WS_B1);
  ushort_t* b2 = (ushort_t*)(ws + WS_B2);
  float* enorm = (float*)(ws + WS_ENORM);
  float4* partials = (float4*)(ws + WS_PART);
  int2* idx2 = (int2*)(ws + WS_IDX2);
  int* counts = (int*)(ws + WS_COUNTS);
  float* lossPart = (float*)(ws + WS_LOSSP);
  ushort_t* xhi = (ushort_t*)(ws + WS_XHI);
  ushort_t* xlo = (ushort_t*)(ws + WS_XLO);

  int fast = (ws_size >= (size_t)WS_FAST_TOTAL) ? 1 : 0;

  hipMemsetAsync(counts, 0, NCODES * sizeof(int), stream);
  k_prep<<<NCODES, 256, 0, stream>>>(embed, embedT, b1, b2, enorm, fast);
  if (fast) {
    k_asplit<<<M_ROWS / 64, 256, 0, stream>>>(inputs, xhi, xlo);
    k_dist_fast<<<8192, 256, 0, stream>>>(xhi, xlo, b1, b2, enorm, partials);
  } else {
    k_dist_slow<<<8192, 256, 0, stream>>>(inputs, b1, b2, enorm, partials);
  }
  k_argmin<<<M_ROWS / 256, 256, 0, stream>>>(partials, idx2);
  k_quant<<<8192, 256, 0, stream>>>(inputs, embedT, idx2, out, out + QELEMS + 2,
                                    counts, lossPart);
  k_final<<<1, 1024, 0, stream>>>(counts, lossPart, out + QELEMS);
}